// Round 3
// baseline (431.952 us; speedup 1.0000x reference)
//
#include <hip/hip_runtime.h>

// PairwiseCost: out[b,i,j] = max(||x[b,i]||^2 + ||y[b,j]||^2 - 2<x[b,i],y[b,j]>, 0)
// B=16, N=2048, D=128, fp32 in/out. bf16 MFMA cross term, fp32-exact norms.
//
// R3: throughput via TLP, not ILP. R0-R2 all ran at 2 waves/SIMD (21% occupancy)
// and landed at the same ~167 us latency wall (MfmaUtil 4%, VALUBusy 9%, HBM 29%
// -- nothing saturated). This version:
//  - one block = one 64(i) x 128(j) tile; NO LDS, NO barriers, no loop.
//  - per-wave 32x64 tile -> ~110 VGPR -> 4 waves/SIMD, grid = 8192 blocks
//    (32 per CU): many independent blocks at random phases keep load, MFMA and
//    store pipes simultaneously fed (wave-drift pipelining).
//  - x and y fragments read straight from global (L2-resident slices);
//    norms computed fp32-exact from the same loads, reduced with shuffles.
//  - regular float4 stores (no nontemporal): L2 merges the 16-row x 64B
//    segments into full lines.

#define Bb 16
#define Nn 2048
#define Dd 128
#define BM 64    // i-rows per block
#define BN 128   // j-cols per block

typedef __bf16 bf16x8 __attribute__((ext_vector_type(8)));
typedef float  f32x4  __attribute__((ext_vector_type(4)));

__device__ __forceinline__ bf16x8 pack8(float4 a, float4 b) {
  // compiler emits v_cvt_pk_bf16_f32 pairs (RTNE)
  bf16x8 r;
  r[0] = (__bf16)a.x; r[1] = (__bf16)a.y; r[2] = (__bf16)a.z; r[3] = (__bf16)a.w;
  r[4] = (__bf16)b.x; r[5] = (__bf16)b.y; r[6] = (__bf16)b.z; r[7] = (__bf16)b.w;
  return r;
}

__global__ __launch_bounds__(256, 4)
void pairwise_cost_kernel(const float* __restrict__ x,
                          const float* __restrict__ y,
                          float* __restrict__ out) {
  const int t  = threadIdx.x;
  const int b  = blockIdx.z;
  const int i0 = blockIdx.y * BM;
  const int j0 = blockIdx.x * BN;

  const int w    = t >> 6;
  const int lane = t & 63;
  const int lrow = lane & 15;     // fragment row index
  const int quad = lane >> 4;     // k-octet
  const int ib   = (w >> 1) * 32; // wave's i-offset in the 64-row tile
  const int jb   = (w & 1) * 64;  // wave's j-offset in the 128-col tile

  // ---- x fragments + fp32-exact row norms (registers only) ----
  bf16x8 xf[2][4];   // [ti][k]
  float  xn[2];
  {
    const float* xb = x + ((size_t)b * Nn + i0 + ib) * Dd;
    #pragma unroll
    for (int ti = 0; ti < 2; ++ti) {
      const float* rp = xb + (ti * 16 + lrow) * Dd + quad * 8;
      float ss = 0.f;
      #pragma unroll
      for (int k = 0; k < 4; ++k) {
        float4 u0 = *(const float4*)(rp + k * 32);
        float4 u1 = *(const float4*)(rp + k * 32 + 4);
        ss += u0.x * u0.x + u0.y * u0.y + u0.z * u0.z + u0.w * u0.w
            + u1.x * u1.x + u1.y * u1.y + u1.z * u1.z + u1.w * u1.w;
        xf[ti][k] = pack8(u0, u1);
      }
      ss += __shfl_xor(ss, 16);   // lane holds 32 of 128 elems; sum the 4 quads
      ss += __shfl_xor(ss, 32);
      xn[ti] = ss;
    }
  }

  // ---- y fragments + MFMA, k-chunked; norms accumulated from the fp32 data ----
  f32x4 acc[2][4];
  #pragma unroll
  for (int ti = 0; ti < 2; ++ti)
    #pragma unroll
    for (int tj = 0; tj < 4; ++tj)
      acc[ti][tj] = (f32x4){0.f, 0.f, 0.f, 0.f};

  float ssy[4] = {0.f, 0.f, 0.f, 0.f};
  {
    const float* yb = y + ((size_t)b * Nn + j0 + jb) * Dd;
    #pragma unroll
    for (int k = 0; k < 4; ++k) {
      bf16x8 yf[4];
      #pragma unroll
      for (int tj = 0; tj < 4; ++tj) {
        const float* rp = yb + (tj * 16 + lrow) * Dd + k * 32 + quad * 8;
        float4 u0 = *(const float4*)(rp);
        float4 u1 = *(const float4*)(rp + 4);
        ssy[tj] += u0.x * u0.x + u0.y * u0.y + u0.z * u0.z + u0.w * u0.w
                 + u1.x * u1.x + u1.y * u1.y + u1.z * u1.z + u1.w * u1.w;
        yf[tj] = pack8(u0, u1);
      }
      // swapped operands: A=y => D rows are j, cols are i
      #pragma unroll
      for (int ti = 0; ti < 2; ++ti)
        #pragma unroll
        for (int tj = 0; tj < 4; ++tj)
          acc[ti][tj] = __builtin_amdgcn_mfma_f32_16x16x32_bf16(yf[tj], xf[ti][k],
                                                               acc[ti][tj], 0, 0, 0);
    }
  }

  // finish y norms: lane holds yn for row (jb + tj*16 + lrow), replicated over quads
  float yn[4];
  #pragma unroll
  for (int tj = 0; tj < 4; ++tj) {
    float s = ssy[tj];
    s += __shfl_xor(s, 16);
    s += __shfl_xor(s, 32);
    yn[tj] = s;
  }

  // ---- epilogue: D layout col=lane&15 (i-sub), row=quad*4+rg (j-sub) ----
  // lane stores float4 of 4 consecutive j at fixed i; yn for those j's comes
  // from lanes (quad*4+rg) via bpermute.
  f32x4 yn4[4];
  #pragma unroll
  for (int tj = 0; tj < 4; ++tj)
    #pragma unroll
    for (int rg = 0; rg < 4; ++rg)
      yn4[tj][rg] = __shfl(yn[tj], quad * 4 + rg);

  float* outb = out + (size_t)b * Nn * Nn;
  #pragma unroll
  for (int ti = 0; ti < 2; ++ti) {
    const size_t orow = (size_t)(i0 + ib + ti * 16 + lrow) * Nn + (j0 + jb);
    const float  xnv  = xn[ti];
    #pragma unroll
    for (int tj = 0; tj < 4; ++tj) {
      f32x4 a = acc[ti][tj];
      f32x4 c;
      #pragma unroll
      for (int rg = 0; rg < 4; ++rg)
        c[rg] = fmaxf(xnv + yn4[tj][rg] - 2.0f * a[rg], 0.0f);
      *(f32x4*)(outb + orow + tj * 16 + quad * 4) = c;
    }
  }
}

extern "C" void kernel_launch(void* const* d_in, const int* in_sizes, int n_in,
                              void* d_out, int out_size, void* d_ws, size_t ws_size,
                              hipStream_t stream) {
  const float* x = (const float*)d_in[0];
  const float* y = (const float*)d_in[1];
  float* out = (float*)d_out;
  dim3 grid(Nn / BN, Nn / BM, Bb);
  pairwise_cost_kernel<<<grid, dim3(256, 1, 1), 0, stream>>>(x, y, out);
}

// Round 5
// 327.738 us; speedup vs baseline: 1.3180x; 1.3180x over previous
//
#include <hip/hip_runtime.h>

// PairwiseCost: out[b,i,j] = max(||x[b,i]||^2 + ||y[b,j]||^2 - 2<x[b,i],y[b,j]>, 0)
// B=16, N=2048, D=128, fp32 in/out.
//
// R5 (= R4 resubmit after container failure, + full unroll of the j-loop).
//  1) precvt: x,y -> bf16 copies in workspace + fp32-exact row norms.
//  2) main:   zero LDS / zero barriers / zero conversion. Per wave: 32(i)x256(j)
//     run as 8 tiles of 32x32. Loads for tile t+1 are issued BEFORE stores of
//     tile t, so the wait before MFMA(t+1) is a counted vmcnt(N) and stores
//     drain in the background (vmcnt is FIFO: a load-wait issued after stores
//     would force a full store drain -- the structural bug in R0-R3).
// Grid 2048 blocks (8/CU), target 3 waves/SIMD.

#define Bb 16
#define Nn 2048
#define Dd 128

typedef __bf16 bf16x8 __attribute__((ext_vector_type(8)));
typedef float  f32x4  __attribute__((ext_vector_type(4)));

__device__ __forceinline__ bf16x8 pack8(float4 a, float4 b) {
  bf16x8 r;
  r[0] = (__bf16)a.x; r[1] = (__bf16)a.y; r[2] = (__bf16)a.z; r[3] = (__bf16)a.w;
  r[4] = (__bf16)b.x; r[5] = (__bf16)b.y; r[6] = (__bf16)b.z; r[7] = (__bf16)b.w;
  return r;
}

// ---------------- pre-pass: fp32 -> bf16 + row norms ----------------
__global__ __launch_bounds__(256)
void precvt_kernel(const float* __restrict__ x, const float* __restrict__ y,
                   __bf16* __restrict__ xb, __bf16* __restrict__ yb,
                   float* __restrict__ xn, float* __restrict__ yn) {
  const int gid  = blockIdx.x * 256 + threadIdx.x;
  const int row  = gid >> 1;          // 0 .. B*N-1
  const int half = gid & 1;           // 64-elem half of the row
  const float* src = (blockIdx.y ? y : x) + (size_t)row * Dd + half * 64;
  __bf16*      dst = (blockIdx.y ? yb : xb) + (size_t)row * Dd + half * 64;
  float*       nrm = blockIdx.y ? yn : xn;

  float ss = 0.f;
  #pragma unroll
  for (int q = 0; q < 8; ++q) {
    float4 u0 = *(const float4*)(src + q * 8);
    float4 u1 = *(const float4*)(src + q * 8 + 4);
    ss += u0.x * u0.x + u0.y * u0.y + u0.z * u0.z + u0.w * u0.w
        + u1.x * u1.x + u1.y * u1.y + u1.z * u1.z + u1.w * u1.w;
    *(bf16x8*)(dst + q * 8) = pack8(u0, u1);
  }
  ss += __shfl_xor(ss, 1);
  if (half == 0) nrm[row] = ss;
}

// ---------------- main kernel ----------------
__global__ __launch_bounds__(256, 3)
void pairwise_main(const __bf16* __restrict__ xb, const __bf16* __restrict__ yb,
                   const float* __restrict__ xn, const float* __restrict__ yn,
                   float* __restrict__ out) {
  const int t    = threadIdx.x;
  const int w    = t >> 6;
  const int lane = t & 63;
  const int lrow = lane & 15;
  const int quad = lane >> 4;

  const int b  = blockIdx.z;
  const int i0 = blockIdx.y * 32;                 // block's 32-row i-strip
  const int j0 = blockIdx.x * 1024 + w * 256;     // wave's exclusive 256-col j-run

  // x fragments + norms (once per wave)
  bf16x8 xf[2][4];
  float  xnr[2];
  {
    const __bf16* xrow = xb + ((size_t)b * Nn + i0) * Dd;
    #pragma unroll
    for (int ti = 0; ti < 2; ++ti) {
      #pragma unroll
      for (int k = 0; k < 4; ++k)
        xf[ti][k] = *(const bf16x8*)(xrow + (size_t)(ti * 16 + lrow) * Dd + k * 32 + quad * 8);
      xnr[ti] = xn[b * Nn + i0 + ti * 16 + lrow];
    }
  }

  const __bf16* ybase = yb + (size_t)b * Nn * Dd;
  const float*  ynb   = yn + b * Nn;
  float*        outb  = out + (size_t)b * Nn * Nn;

  // prefetch tile 0
  bf16x8 yf[2][4];
  f32x4  yn4[2];
  #pragma unroll
  for (int tj = 0; tj < 2; ++tj) {
    #pragma unroll
    for (int k = 0; k < 4; ++k)
      yf[tj][k] = *(const bf16x8*)(ybase + (size_t)(j0 + tj * 16 + lrow) * Dd + k * 32 + quad * 8);
    yn4[tj] = *(const f32x4*)(ynb + j0 + tj * 16 + quad * 4);
  }

  #pragma unroll
  for (int jt = 0; jt < 8; ++jt) {
    const int jc = j0 + jt * 32;

    // (A) prefetch next tile -- issued BEFORE this tile's stores
    bf16x8 yfn[2][4];
    f32x4  yn4n[2];
    if (jt + 1 < 8) {
      const int jcn = j0 + (jt + 1) * 32;
      #pragma unroll
      for (int tj = 0; tj < 2; ++tj) {
        #pragma unroll
        for (int k = 0; k < 4; ++k)
          yfn[tj][k] = *(const bf16x8*)(ybase + (size_t)(jcn + tj * 16 + lrow) * Dd + k * 32 + quad * 8);
        yn4n[tj] = *(const f32x4*)(ynb + jcn + tj * 16 + quad * 4);
      }
    }

    // (B) MFMA: swapped operands (A=y) => acc regs are 4 consecutive j
    f32x4 acc[2][2];
    #pragma unroll
    for (int ti = 0; ti < 2; ++ti)
      #pragma unroll
      for (int tj = 0; tj < 2; ++tj)
        acc[ti][tj] = (f32x4){0.f, 0.f, 0.f, 0.f};
    #pragma unroll
    for (int k = 0; k < 4; ++k)
      #pragma unroll
      for (int ti = 0; ti < 2; ++ti)
        #pragma unroll
        for (int tj = 0; tj < 2; ++tj)
          acc[ti][tj] = __builtin_amdgcn_mfma_f32_16x16x32_bf16(yf[tj][k], xf[ti][k],
                                                               acc[ti][tj], 0, 0, 0);

    // (C) epilogue: D layout col=lane&15 (i-sub), row=quad*4+rg (j-sub)
    #pragma unroll
    for (int ti = 0; ti < 2; ++ti) {
      const size_t orow = (size_t)(i0 + ti * 16 + lrow) * Nn;
      const float  xnv  = xnr[ti];
      #pragma unroll
      for (int tj = 0; tj < 2; ++tj) {
        f32x4 a = acc[ti][tj];
        f32x4 c;
        #pragma unroll
        for (int rg = 0; rg < 4; ++rg)
          c[rg] = fmaxf(xnv + yn4[tj][rg] - 2.0f * a[rg], 0.0f);
        __builtin_nontemporal_store(c, (f32x4*)(outb + orow + jc + tj * 16 + quad * 4));
      }
    }

    // rotate prefetch -> current (full unroll: register-renamed away)
    if (jt + 1 < 8) {
      #pragma unroll
      for (int tj = 0; tj < 2; ++tj) {
        #pragma unroll
        for (int k = 0; k < 4; ++k) yf[tj][k] = yfn[tj][k];
        yn4[tj] = yn4n[tj];
      }
    }
  }
}

// ---------------- fallback (R3, used only if workspace too small) ----------------
__global__ __launch_bounds__(256, 4)
void pairwise_fallback(const float* __restrict__ x, const float* __restrict__ y,
                       float* __restrict__ out) {
  const int t = threadIdx.x, b = blockIdx.z;
  const int i0 = blockIdx.y * 64, j0 = blockIdx.x * 128;
  const int w = t >> 6, lane = t & 63, lrow = lane & 15, quad = lane >> 4;
  const int ib = (w >> 1) * 32, jb = (w & 1) * 64;

  bf16x8 xf[2][4]; float xn[2];
  {
    const float* xbp = x + ((size_t)b * Nn + i0 + ib) * Dd;
    #pragma unroll
    for (int ti = 0; ti < 2; ++ti) {
      const float* rp = xbp + (ti * 16 + lrow) * Dd + quad * 8;
      float ss = 0.f;
      #pragma unroll
      for (int k = 0; k < 4; ++k) {
        float4 u0 = *(const float4*)(rp + k * 32);
        float4 u1 = *(const float4*)(rp + k * 32 + 4);
        ss += u0.x*u0.x+u0.y*u0.y+u0.z*u0.z+u0.w*u0.w
            + u1.x*u1.x+u1.y*u1.y+u1.z*u1.z+u1.w*u1.w;
        xf[ti][k] = pack8(u0, u1);
      }
      ss += __shfl_xor(ss, 16); ss += __shfl_xor(ss, 32);
      xn[ti] = ss;
    }
  }
  f32x4 acc[2][4];
  #pragma unroll
  for (int ti = 0; ti < 2; ++ti)
    #pragma unroll
    for (int tj = 0; tj < 4; ++tj) acc[ti][tj] = (f32x4){0.f,0.f,0.f,0.f};
  float ssy[4] = {0.f,0.f,0.f,0.f};
  {
    const float* ybp = y + ((size_t)b * Nn + j0 + jb) * Dd;
    #pragma unroll
    for (int k = 0; k < 4; ++k) {
      bf16x8 yfr[4];
      #pragma unroll
      for (int tj = 0; tj < 4; ++tj) {
        const float* rp = ybp + (tj * 16 + lrow) * Dd + k * 32 + quad * 8;
        float4 u0 = *(const float4*)(rp);
        float4 u1 = *(const float4*)(rp + 4);
        ssy[tj] += u0.x*u0.x+u0.y*u0.y+u0.z*u0.z+u0.w*u0.w
                 + u1.x*u1.x+u1.y*u1.y+u1.z*u1.z+u1.w*u1.w;
        yfr[tj] = pack8(u0, u1);
      }
      #pragma unroll
      for (int ti = 0; ti < 2; ++ti)
        #pragma unroll
        for (int tj = 0; tj < 4; ++tj)
          acc[ti][tj] = __builtin_amdgcn_mfma_f32_16x16x32_bf16(yfr[tj], xf[ti][k],
                                                               acc[ti][tj], 0, 0, 0);
    }
  }
  float yn[4];
  #pragma unroll
  for (int tj = 0; tj < 4; ++tj) {
    float s = ssy[tj];
    s += __shfl_xor(s, 16); s += __shfl_xor(s, 32);
    yn[tj] = s;
  }
  f32x4 yn4[4];
  #pragma unroll
  for (int tj = 0; tj < 4; ++tj)
    #pragma unroll
    for (int rg = 0; rg < 4; ++rg) yn4[tj][rg] = __shfl(yn[tj], quad * 4 + rg);
  float* outb = out + (size_t)b * Nn * Nn;
  #pragma unroll
  for (int ti = 0; ti < 2; ++ti) {
    const size_t orow = (size_t)(i0 + ib + ti * 16 + lrow) * Nn + (j0 + jb);
    #pragma unroll
    for (int tj = 0; tj < 4; ++tj) {
      f32x4 a = acc[ti][tj]; f32x4 c;
      #pragma unroll
      for (int rg = 0; rg < 4; ++rg)
        c[rg] = fmaxf(xn[ti] + yn4[tj][rg] - 2.0f * a[rg], 0.0f);
      *(f32x4*)(outb + orow + tj * 16 + quad * 4) = c;
    }
  }
}

extern "C" void kernel_launch(void* const* d_in, const int* in_sizes, int n_in,
                              void* d_out, int out_size, void* d_ws, size_t ws_size,
                              hipStream_t stream) {
  const float* x = (const float*)d_in[0];
  const float* y = (const float*)d_in[1];
  float* out = (float*)d_out;

  const size_t bf_elems = (size_t)Bb * Nn * Dd;
  const size_t need = 2 * bf_elems * sizeof(__bf16) + 2 * (size_t)Bb * Nn * sizeof(float);

  if (ws_size >= need && d_ws) {
    __bf16* xbp = (__bf16*)d_ws;
    __bf16* ybp = xbp + bf_elems;
    float*  xnp = (float*)(ybp + bf_elems);
    float*  ynp = xnp + (size_t)Bb * Nn;
    precvt_kernel<<<dim3((Bb * Nn * 2) / 256, 2, 1), dim3(256, 1, 1), 0, stream>>>(
        x, y, xbp, ybp, xnp, ynp);
    pairwise_main<<<dim3(Nn / 1024, Nn / 32, Bb), dim3(256, 1, 1), 0, stream>>>(
        xbp, ybp, xnp, ynp, out);
  } else {
    pairwise_fallback<<<dim3(Nn / 128, Nn / 64, Bb), dim3(256, 1, 1), 0, stream>>>(x, y, out);
  }
}